// Round 1
// baseline (344.299 us; speedup 1.0000x reference)
//
#include <hip/hip_runtime.h>

#define HH 256
#define WW 256
#define CC 64
#define BB 2
#define KK2 9
#define CG 16          // channels per block
#define HWSZ (HH * WW)

__global__ __launch_bounds__(256, 4) void dcn_kernel(
    const float* __restrict__ x,
    const float* __restrict__ offset,
    const float* __restrict__ mask,
    const float* __restrict__ weight,
    float* __restrict__ out)
{
    const int w   = threadIdx.x;           // 0..255 (full row)
    const int row = blockIdx.x;            // 0..B*H-1
    const int h   = row & (HH - 1);
    const int b   = row >> 8;              // H == 256
    const int c0  = blockIdx.y * CG;
    const int hw  = h * WW + w;

    const float* offb  = offset + (size_t)b * 2 * KK2 * HWSZ + hw;
    const float* maskb = mask   + (size_t)b * KK2 * HWSZ + hw;
    const float* xb0   = x      + ((size_t)b * CC + c0) * HWSZ;

    float acc[CG];
#pragma unroll
    for (int c = 0; c < CG; ++c) acc[c] = 0.f;

    for (int k = 0; k < KK2; ++k) {
        const int ki = k / 3;
        const int kj = k - 3 * ki;
        float offy = offb[(2 * k)     * HWSZ];
        float offx = offb[(2 * k + 1) * HWSZ];
        float mval = maskb[k * HWSZ] * weight[k];

        float py = (float)(h - 1 + ki) + offy;
        float px = (float)(w - 1 + kj) + offx;
        float y0f = floorf(py), x0f = floorf(px);
        float ly = py - y0f, lx = px - x0f;
        float hy = 1.f - ly, hx = 1.f - lx;
        int y0 = (int)y0f, x0 = (int)x0f;
        int y1 = y0 + 1,   x1 = x0 + 1;

        // validity per corner coordinate (reference: 0 <= c <= dim-1)
        bool vy0 = (unsigned)y0 < (unsigned)HH;
        bool vy1 = (unsigned)y1 < (unsigned)HH;
        bool vx0 = (unsigned)x0 < (unsigned)WW;
        bool vx1 = (unsigned)x1 < (unsigned)WW;
        int y0c = min(max(y0, 0), HH - 1);
        int y1c = min(max(y1, 0), HH - 1);
        int x0c = min(max(x0, 0), WW - 1);
        int x1c = min(max(x1, 0), WW - 1);

        float w00 = hy * hx * mval * (float)(vy0 && vx0);
        float w01 = hy * lx * mval * (float)(vy0 && vx1);
        float w10 = ly * hx * mval * (float)(vy1 && vx0);
        float w11 = ly * lx * mval * (float)(vy1 && vx1);

        int i00 = y0c * WW + x0c;
        int i01 = y0c * WW + x1c;
        int i10 = y1c * WW + x0c;
        int i11 = y1c * WW + x1c;

        const float* xb = xb0;
#pragma unroll
        for (int c = 0; c < CG; ++c) {
            float v00 = xb[i00];
            float v01 = xb[i01];
            float v10 = xb[i10];
            float v11 = xb[i11];
            acc[c] = fmaf(w00, v00,
                     fmaf(w01, v01,
                     fmaf(w10, v10,
                     fmaf(w11, v11, acc[c]))));
            xb += HWSZ;
        }
    }

    float* ob = out + ((size_t)b * CC + c0) * HWSZ + hw;
#pragma unroll
    for (int c = 0; c < CG; ++c) ob[c * HWSZ] = acc[c];
}

extern "C" void kernel_launch(void* const* d_in, const int* in_sizes, int n_in,
                              void* d_out, int out_size, void* d_ws, size_t ws_size,
                              hipStream_t stream) {
    const float* x      = (const float*)d_in[0];
    const float* offset = (const float*)d_in[1];
    const float* mask   = (const float*)d_in[2];
    const float* weight = (const float*)d_in[3];
    float* out = (float*)d_out;

    dim3 grid(BB * HH, CC / CG);
    dim3 block(WW);
    dcn_kernel<<<grid, block, 0, stream>>>(x, offset, mask, weight, out);
}